// Round 18
// baseline (237.728 us; speedup 1.0000x reference)
//
#include <hip/hip_runtime.h>
#include <cstdint>

typedef float f32x4 __attribute__((ext_vector_type(4)));
typedef short s16x8 __attribute__((ext_vector_type(8)));

#define APAD 72   // padded row (bf16) for b128-read tiles: 144 B rows, 16B-aligned
#define TPAD 68   // padded row (bf16) for u32-only tiles: 2-way-conflict floor

__device__ __forceinline__ unsigned short f2bf(float f) {
  union { float f; uint32_t u; } v; v.f = f;
  uint32_t u = v.u;
  u += 0x7fffu + ((u >> 16) & 1u);
  return (unsigned short)(u >> 16);
}
__device__ __forceinline__ float bf2f(unsigned short h) {
  union { uint32_t u; float f; } v; v.u = ((uint32_t)h) << 16;
  return v.f;
}
// packed f32x2 -> bf16x2 (lo = a, hi = b), single VALU op
__device__ __forceinline__ uint32_t pkbf(float a, float b) {
  uint32_t r;
  asm("v_cvt_pk_bf16_f32 %0, %1, %2" : "=v"(r) : "v"(a), "v"(b));
  return r;
}
// raw v_rcp_f32 (~22-bit accurate; output is bf16-rounded downstream)
__device__ __forceinline__ float fast_rcp(float x) {
  float r;
  asm("v_rcp_f32 %0, %1" : "=v"(r) : "v"(x));
  return r;
}
__device__ __forceinline__ float sigmoidf_(float x) {
  return fast_rcp(1.0f + __expf(-x));
}
__device__ __forceinline__ f32x4 zero4() {
  f32x4 z = {0.f, 0.f, 0.f, 0.f};
  return z;
}
__device__ __forceinline__ void gl_lds16(const void* g, void* l) {
  __builtin_amdgcn_global_load_lds(
      (const __attribute__((address_space(1))) uint32_t*)g,
      (__attribute__((address_space(3))) uint32_t*)l, 16, 0, 0);
}

// ---------------------------------------------------------------------------
// prep: transpose 6 weight matrices [k][n] fp32 -> wt bf16 [m][n][APAD]
// ---------------------------------------------------------------------------
__global__ __launch_bounds__(256) void k_prep(
    const float* __restrict__ Wlp, const float* __restrict__ Wrp,
    const float* __restrict__ Wlg, const float* __restrict__ Wrg,
    const float* __restrict__ Wog, const float* __restrict__ Wout,
    unsigned short* __restrict__ wt) {
  const float* srcs[6] = {Wlp, Wrp, Wlg, Wrg, Wog, Wout};
  const int m = blockIdx.x;
  const float* W = srcs[m];
  const int t = threadIdx.x;
  for (int e = t; e < 64 * APAD; e += 256) {
    const int n = e / APAD, k = e - n * APAD;
    wt[m * (64 * APAD) + e] = (k < 64) ? f2bf(W[k * 64 + n]) : (unsigned short)0;
  }
}

// ---------------------------------------------------------------------------
// k1: x = LN(in); left=(x@Wlp+blp)*mask*sig(x@Wlg+blg); right analog.
// TL/TR use TPAD(68) rows (u32 ops only) -> LDS 26.6 KB -> 6 blocks/CU.
// ---------------------------------------------------------------------------
__global__ __launch_bounds__(256, 6) void k1_proj(
    const float* __restrict__ xin, const float* __restrict__ mask,
    const float* __restrict__ lnw, const float* __restrict__ lnb,
    const float* __restrict__ blp, const float* __restrict__ brp,
    const float* __restrict__ blg, const float* __restrict__ brg,
    const unsigned short* __restrict__ wt,
    unsigned short* __restrict__ leftT, unsigned short* __restrict__ rightT) {
  __shared__ unsigned short A[64 * APAD];
  __shared__ unsigned short TL[64 * TPAD];
  __shared__ unsigned short TR[64 * TPAD];
  const int tid = threadIdx.x, lane = tid & 63, w = tid >> 6;
  const int bid = blockIdx.x;
  const int b = bid >> 12;
  const int i = (bid >> 3) & 511;
  const int k0 = (bid & 7) << 6;

  const int pair = w >> 1, ch = w & 1;
  const int kh8 = (lane >> 4) << 3;
  s16x8 wp[2][2], wg[2][2];
  float bPv[2], bGv[2];
  {
    const unsigned short* wtP = wt + (size_t)pair * (64 * APAD);
    const unsigned short* wtG = wt + (size_t)(2 + pair) * (64 * APAD);
    const float* bP = pair ? brp : blp;
    const float* bG = pair ? brg : blg;
#pragma unroll
    for (int nf2 = 0; nf2 < 2; ++nf2) {
      const int n = ch * 32 + nf2 * 16 + (lane & 15);
      const unsigned short* pp = wtP + n * APAD + kh8;
      const unsigned short* pg = wtG + n * APAD + kh8;
      wp[nf2][0] = *(const s16x8*)pp;  wp[nf2][1] = *(const s16x8*)(pp + 32);
      wg[nf2][0] = *(const s16x8*)pg;  wg[nf2][1] = *(const s16x8*)(pg + 32);
      bPv[nf2] = bP[n];  bGv[nf2] = bG[n];
    }
  }

  const int p = tid >> 2, q = tid & 3;
  const float* xrow = xin + (((size_t)b * 512 + i) * 512 + k0 + p) * 64 + q * 16;
  f32x4 xv[4];
#pragma unroll
  for (int u = 0; u < 4; ++u) xv[u] = ((const f32x4*)xrow)[u];
  float s1 = 0.f, s2 = 0.f;
#pragma unroll
  for (int u = 0; u < 4; ++u)
#pragma unroll
    for (int e = 0; e < 4; ++e) { float t = xv[u][e]; s1 += t; s2 += t * t; }
  s1 += __shfl_xor(s1, 1); s2 += __shfl_xor(s2, 1);
  s1 += __shfl_xor(s1, 2); s2 += __shfl_xor(s2, 2);
  const float mu = s1 * 0.015625f;
  const float rs = rsqrtf(s2 * 0.015625f - mu * mu + 1e-5f);
  {
    uint32_t pk[8];
#pragma unroll
    for (int u = 0; u < 4; ++u) {
      f32x4 wv = ((const f32x4*)(lnw + q * 16))[u];
      f32x4 bv = ((const f32x4*)(lnb + q * 16))[u];
#pragma unroll
      for (int e2 = 0; e2 < 2; ++e2) {
        pk[u * 2 + e2] = pkbf((xv[u][2 * e2] - mu) * rs * wv[2 * e2] + bv[2 * e2],
                              (xv[u][2 * e2 + 1] - mu) * rs * wv[2 * e2 + 1] + bv[2 * e2 + 1]);
      }
    }
    uint32_t* a32 = (uint32_t*)&A[p * APAD + q * 16];
#pragma unroll
    for (int u = 0; u < 8; ++u) a32[u] = pk[u];
  }
  const float mval = mask[b * 512 + i];
  __syncthreads();

  const int fr4 = (lane >> 4) << 2;
  unsigned short* T = pair ? TR : TL;
#pragma unroll
  for (int mf = 0; mf < 4; ++mf) {
    const int ar = (mf * 16 + (lane & 15)) * APAD + kh8;
    const s16x8 a0 = *(const s16x8*)&A[ar];
    const s16x8 a1 = *(const s16x8*)&A[ar + 32];
    f32x4 accP[2], accG[2];
#pragma unroll
    for (int nf2 = 0; nf2 < 2; ++nf2) {
      accP[nf2] = zero4(); accG[nf2] = zero4();
      accP[nf2] = __builtin_amdgcn_mfma_f32_16x16x32_bf16(a0, wp[nf2][0], accP[nf2], 0, 0, 0);
      accP[nf2] = __builtin_amdgcn_mfma_f32_16x16x32_bf16(a1, wp[nf2][1], accP[nf2], 0, 0, 0);
      accG[nf2] = __builtin_amdgcn_mfma_f32_16x16x32_bf16(a0, wg[nf2][0], accG[nf2], 0, 0, 0);
      accG[nf2] = __builtin_amdgcn_mfma_f32_16x16x32_bf16(a1, wg[nf2][1], accG[nf2], 0, 0, 0);
    }
    const int prow = mf * 16 + fr4;
#pragma unroll
    for (int nf2 = 0; nf2 < 2; ++nf2) {
      const int n = ch * 32 + nf2 * 16 + (lane & 15);
      const float bl = bPv[nf2], bg = bGv[nf2];
      float v0 = (accP[nf2][0] + bl) * mval * sigmoidf_(accG[nf2][0] + bg);
      float v1 = (accP[nf2][1] + bl) * mval * sigmoidf_(accG[nf2][1] + bg);
      float v2 = (accP[nf2][2] + bl) * mval * sigmoidf_(accG[nf2][2] + bg);
      float v3 = (accP[nf2][3] + bl) * mval * sigmoidf_(accG[nf2][3] + bg);
      *(uint32_t*)&T[n * TPAD + prow] = pkbf(v0, v1);
      *(uint32_t*)&T[n * TPAD + prow + 2] = pkbf(v2, v3);
    }
  }
  __syncthreads();

  {
    const int sn = tid >> 2, sq = tid & 3;
    const size_t gbase = (((size_t)b * 64 + sn) * 512 + i) * 512 + k0 + sq * 16;
    const uint32_t* sl = (const uint32_t*)&TL[sn * TPAD + sq * 16];
    const uint32_t* sr = (const uint32_t*)&TR[sn * TPAD + sq * 16];
    uint32_t* dl = (uint32_t*)(leftT + gbase);
    uint32_t* dr = (uint32_t*)(rightT + gbase);
#pragma unroll
    for (int u = 0; u < 8; ++u) dl[u] = sl[u];
#pragma unroll
    for (int u = 0; u < 8; ++u) dr[u] = sr[u];
  }
}

// ---------------------------------------------------------------------------
// k2: triT[b,c,i,j] = sum_k leftT[b,c,i,k] * rightT[b,c,j,k]
// BK=32 double-buffer, 32 KB LDS, 4 blocks/CU; XOR-swizzled (rule #21).
// Direct u16 store epilogue (proven r11).
// ---------------------------------------------------------------------------
__global__ __launch_bounds__(256, 4) void k2_gemm(
    const unsigned short* __restrict__ leftT,
    const unsigned short* __restrict__ rightT,
    unsigned short* __restrict__ triT) {
  __shared__ __align__(16) unsigned short S[4 * 4096];   // 32 KB
  const int tid = threadIdx.x, lane = tid & 63, w = tid >> 6;
  const int bid = blockIdx.x;
  const int sw = ((bid & 7) << 8) | (bid >> 3);
  const int plane = sw >> 4, tile = sw & 15;
  const size_t pb = (size_t)plane * 262144;
  const int i0 = (tile >> 2) << 7, j0 = (tile & 3) << 7;
  const int srow = lane >> 2;
  const int sk = (((lane & 3) ^ ((lane >> 2) & 3)) << 3);

  f32x4 acc[4][4];
#pragma unroll
  for (int mf = 0; mf < 4; ++mf)
#pragma unroll
    for (int nf = 0; nf < 4; ++nf) acc[mf][nf] = zero4();
  const int wr = (w >> 1) << 6, wc = (w & 1) << 6;

  auto stage = [&](int buf, int kt) {
    const int kk = kt << 5;
#pragma unroll
    for (int it = 0; it < 2; ++it) {
      const int ch = it * 4 + w;
      const int row = (ch << 4) + srow;
      gl_lds16(leftT + pb + (size_t)(i0 + row) * 512 + kk + sk,
               (char*)S + buf * 16384 + ch * 1024 + lane * 16);
      gl_lds16(rightT + pb + (size_t)(j0 + row) * 512 + kk + sk,
               (char*)S + buf * 16384 + 8192 + ch * 1024 + lane * 16);
    }
  };

  stage(0, 0);
  const int l15 = lane & 15;
  const int kosw = ((lane >> 4) ^ (lane & 3)) << 3;
  for (int kt = 0; kt < 16; ++kt) {
    __syncthreads();
    if (kt < 15) stage((kt & 1) ^ 1, kt + 1);
    const unsigned short* Ac = S + (kt & 1) * 8192;
    const unsigned short* Bc = Ac + 4096;
    s16x8 af[4], bfr[4];
#pragma unroll
    for (int mf = 0; mf < 4; ++mf)
      af[mf] = *(const s16x8*)&Ac[(wr + mf * 16 + l15) * 32 + kosw];
#pragma unroll
    for (int nf = 0; nf < 4; ++nf)
      bfr[nf] = *(const s16x8*)&Bc[(wc + nf * 16 + l15) * 32 + kosw];
#pragma unroll
    for (int mf = 0; mf < 4; ++mf)
#pragma unroll
      for (int nf = 0; nf < 4; ++nf)
        acc[mf][nf] = __builtin_amdgcn_mfma_f32_16x16x32_bf16(af[mf], bfr[nf], acc[mf][nf], 0, 0, 0);
  }
  __syncthreads();   // drain staging before stores
  {
    const int hi4 = (lane >> 4) << 2;
#pragma unroll
    for (int mf = 0; mf < 4; ++mf)
#pragma unroll
      for (int nf = 0; nf < 4; ++nf) {
        const int col = wc + nf * 16 + l15;
        unsigned short* dst =
            triT + pb + (size_t)(i0 + wr + mf * 16 + hi4) * 512 + j0 + col;
#pragma unroll
        for (int r = 0; r < 4; ++r)
          dst[(size_t)r * 512] = f2bf(acc[mf][nf][r]);
      }
  }
}

// ---------------------------------------------------------------------------
// k3 (r12 body; og weights in VGPRs, RELAXED launch bounds — r14 retest
// without the spill-inducing (256,6) cap). LDS = WTout + Y = 18.4 KB.
// ---------------------------------------------------------------------------
__global__ __launch_bounds__(256) void k3_out(
    const unsigned short* __restrict__ triT,
    const float* __restrict__ resid,
    const float* __restrict__ lnw1, const float* __restrict__ lnb1,
    const float* __restrict__ bog,
    const float* __restrict__ lnw2, const float* __restrict__ lnb2,
    const float* __restrict__ bout,
    const unsigned short* __restrict__ wt,
    float* __restrict__ outp) {
  __shared__ __align__(16) unsigned char smem[18432];
  unsigned short* WTout = (unsigned short*)smem;            // [64][APAD]
  unsigned short* Y     = (unsigned short*)(smem + 9216);   // [64][APAD] swz c
  const int tid = threadIdx.x, lane = tid & 63, w = tid >> 6;
  const int bid = blockIdx.x;
  const int b = bid >> 12;
  const int i = (bid >> 3) & 511;
  const int j0 = (bid & 7) << 6;

  const int l15 = lane & 15, hi = lane >> 4;
  const int kh8 = hi << 3;

  // entry: stage out^T to LDS (async); og^T fragments -> VGPRs (L2-hot)
  {
    const char* wsrc = (const char*)(wt + (size_t)5 * (64 * APAD));
#pragma unroll
    for (int it = 0; it < 3; ++it) {
      const int off = (it * 256 + tid) * 16;
      if (off < 9216) gl_lds16(wsrc + off, (char*)WTout + off);
    }
  }
  s16x8 wog0[4], wog1[4];
  {
    const unsigned short* wg = wt + (size_t)4 * (64 * APAD);
#pragma unroll
    for (int nf = 0; nf < 4; ++nf) {
      const unsigned short* p = wg + (nf * 16 + l15) * APAD + kh8;
      wog0[nf] = *(const s16x8*)p;
      wog1[nf] = *(const s16x8*)(p + 32);
    }
  }

  // tri loads issued early (latency hides under the LN VALU below)
  const int q = tid & 3;
  union { uint32_t u32[8]; unsigned short s[16]; } uu;
  {
    const int c = tid >> 2;
    const size_t srow = ((size_t)(b * 64 + c) * 512 + i) * 512 + j0 + q * 16;
    const uint32_t* s32 = (const uint32_t*)(triT + srow);
#pragma unroll
    for (int u = 0; u < 8; ++u) uu.u32[u] = s32[u];
  }

  const int jrow = w * 16 + l15;
  const size_t rowbase = (((size_t)b * 512 + i) * 512 + j0 + jrow) * 64;
  const int lane_a = l15 + ((hi & 1) << 5);
  const int lane_b = lane_a + 16;
  const bool hiU = (hi >> 1) != 0;

  // p1a: resid in OUTPUT layout (read once) -> LN_in -> xb frags via shfl
  f32x4 rx[4];
  s16x8 xb0, xb1;
  {
#pragma unroll
    for (int nf = 0; nf < 4; ++nf)
      rx[nf] = *(const f32x4*)(resid + rowbase + nf * 16 + (hi << 2));
    float s1 = 0.f, s2 = 0.f;
#pragma unroll
    for (int u = 0; u < 4; ++u)
#pragma unroll
      for (int e = 0; e < 4; ++e) { float t = rx[u][e]; s1 += t; s2 += t * t; }
    s1 += __shfl_xor(s1, 16); s2 += __shfl_xor(s2, 16);
    s1 += __shfl_xor(s1, 32); s2 += __shfl_xor(s2, 32);
    const float mu = s1 * 0.015625f;
    const float rs = rsqrtf(s2 * 0.015625f - mu * mu + 1e-5f);
    uint32_t pk8[8];
#pragma unroll
    for (int nf = 0; nf < 4; ++nf) {
      const f32x4 wv = *(const f32x4*)(lnw1 + nf * 16 + (hi << 2));
      const f32x4 bv = *(const f32x4*)(lnb1 + nf * 16 + (hi << 2));
      const float z0 = (rx[nf][0] - mu) * rs * wv[0] + bv[0];
      const float z1 = (rx[nf][1] - mu) * rs * wv[1] + bv[1];
      const float z2 = (rx[nf][2] - mu) * rs * wv[2] + bv[2];
      const float z3 = (rx[nf][3] - mu) * rs * wv[3] + bv[3];
      pk8[nf * 2] = pkbf(z0, z1);
      pk8[nf * 2 + 1] = pkbf(z2, z3);
    }
    union { uint32_t u[4]; s16x8 v; } f0, f1;
    {
      uint32_t a0l = __shfl(pk8[0], lane_a), a0h = __shfl(pk8[2], lane_a);
      uint32_t a1l = __shfl(pk8[1], lane_a), a1h = __shfl(pk8[3], lane_a);
      uint32_t b0l = __shfl(pk8[0], lane_b), b0h = __shfl(pk8[2], lane_b);
      uint32_t b1l = __shfl(pk8[1], lane_b), b1h = __shfl(pk8[3], lane_b);
      f0.u[0] = hiU ? a0h : a0l;  f0.u[1] = hiU ? a1h : a1l;
      f0.u[2] = hiU ? b0h : b0l;  f0.u[3] = hiU ? b1h : b1l;
    }
    {
      uint32_t a0l = __shfl(pk8[4], lane_a), a0h = __shfl(pk8[6], lane_a);
      uint32_t a1l = __shfl(pk8[5], lane_a), a1h = __shfl(pk8[7], lane_a);
      uint32_t b0l = __shfl(pk8[4], lane_b), b0h = __shfl(pk8[6], lane_b);
      uint32_t b1l = __shfl(pk8[5], lane_b), b1h = __shfl(pk8[7], lane_b);
      f1.u[0] = hiU ? a0h : a0l;  f1.u[1] = hiU ? a1h : a1l;
      f1.u[2] = hiU ? b0h : b0l;  f1.u[3] = hiU ? b1h : b1l;
    }
    xb0 = f0.v; xb1 = f1.v;
  }

  // p1b: scatter tri tile -> transposed Y[j][c^((j>>4)<<4)]
  {
    const int c = tid >> 2;
    const int csw = c ^ (q << 4);
#pragma unroll
    for (int s = 0; s < 16; ++s) Y[(q * 16 + s) * APAD + csw] = uu.s[s];
  }
  __syncthreads();   // B1 (drains staging + Y)

  // p2: tri stats + og MFMA (weights from regs) + y -> Y in place
  const int ybase = jrow * APAD;
  float yv[16];
#pragma unroll
  for (int nf = 0; nf < 4; ++nf) {
    const int pc = (((nf ^ w) & 3) << 4) + (hi << 2);
    const uint2 dd = *(const uint2*)&Y[ybase + pc];
    yv[nf * 4 + 0] = bf2f((unsigned short)(dd.x & 0xffff));
    yv[nf * 4 + 1] = bf2f((unsigned short)(dd.x >> 16));
    yv[nf * 4 + 2] = bf2f((unsigned short)(dd.y & 0xffff));
    yv[nf * 4 + 3] = bf2f((unsigned short)(dd.y >> 16));
  }
  float t1 = 0.f, t2 = 0.f;
#pragma unroll
  for (int s = 0; s < 16; ++s) { t1 += yv[s]; t2 += yv[s] * yv[s]; }
  t1 += __shfl_xor(t1, 16); t2 += __shfl_xor(t2, 16);
  t1 += __shfl_xor(t1, 32); t2 += __shfl_xor(t2, 32);
  const float mu2 = t1 * 0.015625f;
  const float rs2 = rsqrtf(t2 * 0.015625f - mu2 * mu2 + 1e-5f);

#pragma unroll
  for (int nf = 0; nf < 4; ++nf) {
    f32x4 aog = zero4();
    aog = __builtin_amdgcn_mfma_f32_16x16x32_bf16(wog0[nf], xb0, aog, 0, 0, 0);
    aog = __builtin_amdgcn_mfma_f32_16x16x32_bf16(wog1[nf], xb1, aog, 0, 0, 0);
    const f32x4 bg4 = *(const f32x4*)(bog + nf * 16 + (hi << 2));
    const f32x4 wv = *(const f32x4*)(lnw2 + nf * 16 + (hi << 2));
    const f32x4 bv = *(const f32x4*)(lnb2 + nf * 16 + (hi << 2));
    const float y0 = ((yv[nf * 4 + 0] - mu2) * rs2 * wv[0] + bv[0]) * sigmoidf_(aog[0] + bg4[0]);
    const float y1 = ((yv[nf * 4 + 1] - mu2) * rs2 * wv[1] + bv[1]) * sigmoidf_(aog[1] + bg4[1]);
    const float y2 = ((yv[nf * 4 + 2] - mu2) * rs2 * wv[2] + bv[2]) * sigmoidf_(aog[2] + bg4[2]);
    const float y3 = ((yv[nf * 4 + 3] - mu2) * rs2 * wv[3] + bv[3]) * sigmoidf_(aog[3] + bg4[3]);
    uint2 o;
    o.x = pkbf(y0, y1);
    o.y = pkbf(y2, y3);
    const int pc = (((nf ^ w) & 3) << 4) + (hi << 2);
    *(uint2*)&Y[ybase + pc] = o;
  }
  __syncthreads();   // B2

  // p3: out = y @ Wout + bout + resid(regs) -> direct f32x4 stores
  {
    const int xsw = w << 4;
    const s16x8 a0 = *(const s16x8*)&Y[ybase + (kh8 ^ xsw)];
    const s16x8 a1 = *(const s16x8*)&Y[ybase + ((32 + kh8) ^ xsw)];
#pragma unroll
    for (int nf = 0; nf < 4; ++nf) {
      const int brow = (nf * 16 + l15) * APAD + kh8;
      const s16x8 wb0 = *(const s16x8*)&WTout[brow];
      const s16x8 wb1 = *(const s16x8*)&WTout[brow + 32];
      f32x4 ao = zero4();
      ao = __builtin_amdgcn_mfma_f32_16x16x32_bf16(wb0, a0, ao, 0, 0, 0);
      ao = __builtin_amdgcn_mfma_f32_16x16x32_bf16(wb1, a1, ao, 0, 0, 0);
      const f32x4 bo4 = *(const f32x4*)(bout + nf * 16 + (hi << 2));
      f32x4 ov = ao + bo4 + rx[nf];
      *(f32x4*)(outp + rowbase + nf * 16 + (hi << 2)) = ov;
    }
  }
}

// ---------------------------------------------------------------------------
extern "C" void kernel_launch(void* const* d_in, const int* in_sizes, int n_in,
                              void* d_out, int out_size, void* d_ws, size_t ws_size,
                              hipStream_t stream) {
  const float* x     = (const float*)d_in[0];
  const float* mask  = (const float*)d_in[1];
  const float* lnw1  = (const float*)d_in[2];
  const float* lnb1  = (const float*)d_in[3];
  const float* Wlp   = (const float*)d_in[4];
  const float* blp   = (const float*)d_in[5];
  const float* Wrp   = (const float*)d_in[6];
  const float* brp   = (const float*)d_in[7];
  const float* Wlg   = (const float*)d_in[8];
  const float* blg   = (const float*)d_in[9];
  const float* Wrg   = (const float*)d_in[10];
  const float* brg   = (const float*)d_in[11];
  const float* Wog   = (const float*)d_in[12];
  const float* bog   = (const float*)d_in[13];
  const float* lnw2  = (const float*)d_in[14];
  const float* lnb2  = (const float*)d_in[15];
  const float* Wout  = (const float*)d_in[16];
  const float* bout  = (const float*)d_in[17];

  unsigned short* leftT  = (unsigned short*)d_ws;
  unsigned short* rightT = leftT + (size_t)33554432;
  unsigned short* triT   = rightT + (size_t)33554432;
  unsigned short* wt     = triT + (size_t)33554432;   // 6*64*APAD bf16

  k_prep<<<6, 256, 0, stream>>>(Wlp, Wrp, Wlg, Wrg, Wog, Wout, wt);
  k1_proj<<<8192, 256, 0, stream>>>(x, mask, lnw1, lnb1, blp, brp, blg, brg,
                                    wt, leftT, rightT);
  k2_gemm<<<2048, 256, 0, stream>>>(leftT, rightT, triT);
  k3_out<<<8192, 256, 0, stream>>>(triT, x, lnw1, lnb1, bog, lnw2, lnb2, bout,
                                   wt, (float*)d_out);
}

// Round 19
// 225.797 us; speedup vs baseline: 1.0528x; 1.0528x over previous
//
#include <hip/hip_runtime.h>
#include <cstdint>

typedef float f32x4 __attribute__((ext_vector_type(4)));
typedef short s16x8 __attribute__((ext_vector_type(8)));

#define APAD 72   // padded row (bf16) for b128-read tiles: 144 B rows, 16B-aligned
#define TPAD 68   // padded row (bf16) for u32-only tiles: 2-way-conflict floor

__device__ __forceinline__ unsigned short f2bf(float f) {
  union { float f; uint32_t u; } v; v.f = f;
  uint32_t u = v.u;
  u += 0x7fffu + ((u >> 16) & 1u);
  return (unsigned short)(u >> 16);
}
__device__ __forceinline__ float bf2f(unsigned short h) {
  union { uint32_t u; float f; } v; v.u = ((uint32_t)h) << 16;
  return v.f;
}
// packed f32x2 -> bf16x2 (lo = a, hi = b), single VALU op
__device__ __forceinline__ uint32_t pkbf(float a, float b) {
  uint32_t r;
  asm("v_cvt_pk_bf16_f32 %0, %1, %2" : "=v"(r) : "v"(a), "v"(b));
  return r;
}
// raw v_rcp_f32 (~22-bit accurate; output is bf16-rounded downstream)
__device__ __forceinline__ float fast_rcp(float x) {
  float r;
  asm("v_rcp_f32 %0, %1" : "=v"(r) : "v"(x));
  return r;
}
__device__ __forceinline__ float sigmoidf_(float x) {
  return fast_rcp(1.0f + __expf(-x));
}
__device__ __forceinline__ f32x4 zero4() {
  f32x4 z = {0.f, 0.f, 0.f, 0.f};
  return z;
}
__device__ __forceinline__ void gl_lds16(const void* g, void* l) {
  __builtin_amdgcn_global_load_lds(
      (const __attribute__((address_space(1))) uint32_t*)g,
      (__attribute__((address_space(3))) uint32_t*)l, 16, 0, 0);
}

// ---------------------------------------------------------------------------
// prep: transpose 6 weight matrices [k][n] fp32 -> wt bf16 [m][n][APAD]
// ---------------------------------------------------------------------------
__global__ __launch_bounds__(256) void k_prep(
    const float* __restrict__ Wlp, const float* __restrict__ Wrp,
    const float* __restrict__ Wlg, const float* __restrict__ Wrg,
    const float* __restrict__ Wog, const float* __restrict__ Wout,
    unsigned short* __restrict__ wt) {
  const float* srcs[6] = {Wlp, Wrp, Wlg, Wrg, Wog, Wout};
  const int m = blockIdx.x;
  const float* W = srcs[m];
  const int t = threadIdx.x;
  for (int e = t; e < 64 * APAD; e += 256) {
    const int n = e / APAD, k = e - n * APAD;
    wt[m * (64 * APAD) + e] = (k < 64) ? f2bf(W[k * 64 + n]) : (unsigned short)0;
  }
}

// ---------------------------------------------------------------------------
// k1: x = LN(in); left=(x@Wlp+blp)*mask*sig(x@Wlg+blg); right analog.
// TL/TR use TPAD(68) rows (u32 ops only) -> LDS 26.6 KB -> 6 blocks/CU.
// ---------------------------------------------------------------------------
__global__ __launch_bounds__(256, 6) void k1_proj(
    const float* __restrict__ xin, const float* __restrict__ mask,
    const float* __restrict__ lnw, const float* __restrict__ lnb,
    const float* __restrict__ blp, const float* __restrict__ brp,
    const float* __restrict__ blg, const float* __restrict__ brg,
    const unsigned short* __restrict__ wt,
    unsigned short* __restrict__ leftT, unsigned short* __restrict__ rightT) {
  __shared__ unsigned short A[64 * APAD];
  __shared__ unsigned short TL[64 * TPAD];
  __shared__ unsigned short TR[64 * TPAD];
  const int tid = threadIdx.x, lane = tid & 63, w = tid >> 6;
  const int bid = blockIdx.x;
  const int b = bid >> 12;
  const int i = (bid >> 3) & 511;
  const int k0 = (bid & 7) << 6;

  const int pair = w >> 1, ch = w & 1;
  const int kh8 = (lane >> 4) << 3;
  s16x8 wp[2][2], wg[2][2];
  float bPv[2], bGv[2];
  {
    const unsigned short* wtP = wt + (size_t)pair * (64 * APAD);
    const unsigned short* wtG = wt + (size_t)(2 + pair) * (64 * APAD);
    const float* bP = pair ? brp : blp;
    const float* bG = pair ? brg : blg;
#pragma unroll
    for (int nf2 = 0; nf2 < 2; ++nf2) {
      const int n = ch * 32 + nf2 * 16 + (lane & 15);
      const unsigned short* pp = wtP + n * APAD + kh8;
      const unsigned short* pg = wtG + n * APAD + kh8;
      wp[nf2][0] = *(const s16x8*)pp;  wp[nf2][1] = *(const s16x8*)(pp + 32);
      wg[nf2][0] = *(const s16x8*)pg;  wg[nf2][1] = *(const s16x8*)(pg + 32);
      bPv[nf2] = bP[n];  bGv[nf2] = bG[n];
    }
  }

  const int p = tid >> 2, q = tid & 3;
  const float* xrow = xin + (((size_t)b * 512 + i) * 512 + k0 + p) * 64 + q * 16;
  f32x4 xv[4];
#pragma unroll
  for (int u = 0; u < 4; ++u) xv[u] = ((const f32x4*)xrow)[u];
  float s1 = 0.f, s2 = 0.f;
#pragma unroll
  for (int u = 0; u < 4; ++u)
#pragma unroll
    for (int e = 0; e < 4; ++e) { float t = xv[u][e]; s1 += t; s2 += t * t; }
  s1 += __shfl_xor(s1, 1); s2 += __shfl_xor(s2, 1);
  s1 += __shfl_xor(s1, 2); s2 += __shfl_xor(s2, 2);
  const float mu = s1 * 0.015625f;
  const float rs = rsqrtf(s2 * 0.015625f - mu * mu + 1e-5f);
  {
    uint32_t pk[8];
#pragma unroll
    for (int u = 0; u < 4; ++u) {
      f32x4 wv = ((const f32x4*)(lnw + q * 16))[u];
      f32x4 bv = ((const f32x4*)(lnb + q * 16))[u];
#pragma unroll
      for (int e2 = 0; e2 < 2; ++e2) {
        pk[u * 2 + e2] = pkbf((xv[u][2 * e2] - mu) * rs * wv[2 * e2] + bv[2 * e2],
                              (xv[u][2 * e2 + 1] - mu) * rs * wv[2 * e2 + 1] + bv[2 * e2 + 1]);
      }
    }
    uint32_t* a32 = (uint32_t*)&A[p * APAD + q * 16];
#pragma unroll
    for (int u = 0; u < 8; ++u) a32[u] = pk[u];
  }
  const float mval = mask[b * 512 + i];
  __syncthreads();

  const int fr4 = (lane >> 4) << 2;
  unsigned short* T = pair ? TR : TL;
#pragma unroll
  for (int mf = 0; mf < 4; ++mf) {
    const int ar = (mf * 16 + (lane & 15)) * APAD + kh8;
    const s16x8 a0 = *(const s16x8*)&A[ar];
    const s16x8 a1 = *(const s16x8*)&A[ar + 32];
    f32x4 accP[2], accG[2];
#pragma unroll
    for (int nf2 = 0; nf2 < 2; ++nf2) {
      accP[nf2] = zero4(); accG[nf2] = zero4();
      accP[nf2] = __builtin_amdgcn_mfma_f32_16x16x32_bf16(a0, wp[nf2][0], accP[nf2], 0, 0, 0);
      accP[nf2] = __builtin_amdgcn_mfma_f32_16x16x32_bf16(a1, wp[nf2][1], accP[nf2], 0, 0, 0);
      accG[nf2] = __builtin_amdgcn_mfma_f32_16x16x32_bf16(a0, wg[nf2][0], accG[nf2], 0, 0, 0);
      accG[nf2] = __builtin_amdgcn_mfma_f32_16x16x32_bf16(a1, wg[nf2][1], accG[nf2], 0, 0, 0);
    }
    const int prow = mf * 16 + fr4;
#pragma unroll
    for (int nf2 = 0; nf2 < 2; ++nf2) {
      const int n = ch * 32 + nf2 * 16 + (lane & 15);
      const float bl = bPv[nf2], bg = bGv[nf2];
      float v0 = (accP[nf2][0] + bl) * mval * sigmoidf_(accG[nf2][0] + bg);
      float v1 = (accP[nf2][1] + bl) * mval * sigmoidf_(accG[nf2][1] + bg);
      float v2 = (accP[nf2][2] + bl) * mval * sigmoidf_(accG[nf2][2] + bg);
      float v3 = (accP[nf2][3] + bl) * mval * sigmoidf_(accG[nf2][3] + bg);
      *(uint32_t*)&T[n * TPAD + prow] = pkbf(v0, v1);
      *(uint32_t*)&T[n * TPAD + prow + 2] = pkbf(v2, v3);
    }
  }
  __syncthreads();

  {
    const int sn = tid >> 2, sq = tid & 3;
    const size_t gbase = (((size_t)b * 64 + sn) * 512 + i) * 512 + k0 + sq * 16;
    const uint32_t* sl = (const uint32_t*)&TL[sn * TPAD + sq * 16];
    const uint32_t* sr = (const uint32_t*)&TR[sn * TPAD + sq * 16];
    uint32_t* dl = (uint32_t*)(leftT + gbase);
    uint32_t* dr = (uint32_t*)(rightT + gbase);
#pragma unroll
    for (int u = 0; u < 8; ++u) dl[u] = sl[u];
#pragma unroll
    for (int u = 0; u < 8; ++u) dr[u] = sr[u];
  }
}

// ---------------------------------------------------------------------------
// k2: triT[b,c,i,j] = sum_k leftT[b,c,i,k] * rightT[b,c,j,k]
// BK=32 double-buffer, 32 KB LDS, 4 blocks/CU; XOR-swizzled (rule #21).
// Direct u16 store epilogue (proven r11).
// ---------------------------------------------------------------------------
__global__ __launch_bounds__(256, 4) void k2_gemm(
    const unsigned short* __restrict__ leftT,
    const unsigned short* __restrict__ rightT,
    unsigned short* __restrict__ triT) {
  __shared__ __align__(16) unsigned short S[4 * 4096];   // 32 KB
  const int tid = threadIdx.x, lane = tid & 63, w = tid >> 6;
  const int bid = blockIdx.x;
  const int sw = ((bid & 7) << 8) | (bid >> 3);
  const int plane = sw >> 4, tile = sw & 15;
  const size_t pb = (size_t)plane * 262144;
  const int i0 = (tile >> 2) << 7, j0 = (tile & 3) << 7;
  const int srow = lane >> 2;
  const int sk = (((lane & 3) ^ ((lane >> 2) & 3)) << 3);

  f32x4 acc[4][4];
#pragma unroll
  for (int mf = 0; mf < 4; ++mf)
#pragma unroll
    for (int nf = 0; nf < 4; ++nf) acc[mf][nf] = zero4();
  const int wr = (w >> 1) << 6, wc = (w & 1) << 6;

  auto stage = [&](int buf, int kt) {
    const int kk = kt << 5;
#pragma unroll
    for (int it = 0; it < 2; ++it) {
      const int ch = it * 4 + w;
      const int row = (ch << 4) + srow;
      gl_lds16(leftT + pb + (size_t)(i0 + row) * 512 + kk + sk,
               (char*)S + buf * 16384 + ch * 1024 + lane * 16);
      gl_lds16(rightT + pb + (size_t)(j0 + row) * 512 + kk + sk,
               (char*)S + buf * 16384 + 8192 + ch * 1024 + lane * 16);
    }
  };

  stage(0, 0);
  const int l15 = lane & 15;
  const int kosw = ((lane >> 4) ^ (lane & 3)) << 3;
  for (int kt = 0; kt < 16; ++kt) {
    __syncthreads();
    if (kt < 15) stage((kt & 1) ^ 1, kt + 1);
    const unsigned short* Ac = S + (kt & 1) * 8192;
    const unsigned short* Bc = Ac + 4096;
    s16x8 af[4], bfr[4];
#pragma unroll
    for (int mf = 0; mf < 4; ++mf)
      af[mf] = *(const s16x8*)&Ac[(wr + mf * 16 + l15) * 32 + kosw];
#pragma unroll
    for (int nf = 0; nf < 4; ++nf)
      bfr[nf] = *(const s16x8*)&Bc[(wc + nf * 16 + l15) * 32 + kosw];
#pragma unroll
    for (int mf = 0; mf < 4; ++mf)
#pragma unroll
      for (int nf = 0; nf < 4; ++nf)
        acc[mf][nf] = __builtin_amdgcn_mfma_f32_16x16x32_bf16(af[mf], bfr[nf], acc[mf][nf], 0, 0, 0);
  }
  __syncthreads();   // drain staging before stores
  {
    const int hi4 = (lane >> 4) << 2;
#pragma unroll
    for (int mf = 0; mf < 4; ++mf)
#pragma unroll
      for (int nf = 0; nf < 4; ++nf) {
        const int col = wc + nf * 16 + l15;
        unsigned short* dst =
            triT + pb + (size_t)(i0 + wr + mf * 16 + hi4) * 512 + j0 + col;
#pragma unroll
        for (int r = 0; r < 4; ++r)
          dst[(size_t)r * 512] = f2bf(acc[mf][nf][r]);
      }
  }
}

// ---------------------------------------------------------------------------
// k3 v5 (best measured): 512-thread blocks, two independent 256-thread halves
// (own Y buffer, own j0) sharing one weight staging. LDS 36.9 KB / 8 waves ->
// 4 blocks/CU = 32 waves/CU cap. Per-half body = proven r12/r16 k3, t=tid&255.
// ---------------------------------------------------------------------------
__global__ __launch_bounds__(512, 6) void k3_out(
    const unsigned short* __restrict__ triT,
    const float* __restrict__ resid,
    const float* __restrict__ lnw1, const float* __restrict__ lnb1,
    const float* __restrict__ bog,
    const float* __restrict__ lnw2, const float* __restrict__ lnb2,
    const float* __restrict__ bout,
    const unsigned short* __restrict__ wt,
    float* __restrict__ outp) {
  __shared__ __align__(16) unsigned char smem[18432 + 2 * 9216];
  unsigned short* WTog  = (unsigned short*)smem;            // [64][APAD]
  unsigned short* WTout = (unsigned short*)(smem + 9216);   // [64][APAD]
  const int tid = threadIdx.x;
  const int half = tid >> 8;          // which j-subtile this half handles
  const int t = tid & 255;
  const int lane = t & 63, w = t >> 6;
  unsigned short* Y = (unsigned short*)(smem + 18432 + half * 9216);
  const int bid = blockIdx.x;
  const int b = bid >> 11;
  const int i = (bid >> 2) & 511;
  const int j0 = ((bid & 3) << 7) + (half << 6);

  // entry: async-stage og^T + out^T (18432 B) using all 512 threads
  {
    const char* wsrc = (const char*)(wt + (size_t)4 * (64 * APAD));
#pragma unroll
    for (int it = 0; it < 3; ++it) {
      const int off = (it * 512 + tid) * 16;
      if (off < 18432) gl_lds16(wsrc + off, (char*)WTog + off);
    }
  }

  // tri loads issued FIRST (latency hides under the LN VALU below)
  const int q = t & 3;
  union { uint32_t u32[8]; unsigned short s[16]; } uu;
  {
    const int c = t >> 2;
    const size_t srow = ((size_t)(b * 64 + c) * 512 + i) * 512 + j0 + q * 16;
    const uint32_t* s32 = (const uint32_t*)(triT + srow);
#pragma unroll
    for (int u = 0; u < 8; ++u) uu.u32[u] = s32[u];
  }

  const int l15 = lane & 15, hi = lane >> 4;
  const int jrow = w * 16 + l15;
  const size_t rowbase = (((size_t)b * 512 + i) * 512 + j0 + jrow) * 64;
  const int kh8 = hi << 3;
  const int lane_a = l15 + ((hi & 1) << 5);
  const int lane_b = lane_a + 16;
  const bool hiU = (hi >> 1) != 0;

  // p1a: resid in OUTPUT layout (read once) -> LN_in -> xb frags via shfl
  f32x4 rx[4];
  s16x8 xb0, xb1;
  {
#pragma unroll
    for (int nf = 0; nf < 4; ++nf)
      rx[nf] = *(const f32x4*)(resid + rowbase + nf * 16 + (hi << 2));
    float s1 = 0.f, s2 = 0.f;
#pragma unroll
    for (int u = 0; u < 4; ++u)
#pragma unroll
      for (int e = 0; e < 4; ++e) { float tv = rx[u][e]; s1 += tv; s2 += tv * tv; }
    s1 += __shfl_xor(s1, 16); s2 += __shfl_xor(s2, 16);
    s1 += __shfl_xor(s1, 32); s2 += __shfl_xor(s2, 32);
    const float mu = s1 * 0.015625f;
    const float rs = rsqrtf(s2 * 0.015625f - mu * mu + 1e-5f);
    uint32_t pk8[8];
#pragma unroll
    for (int nf = 0; nf < 4; ++nf) {
      const f32x4 wv = *(const f32x4*)(lnw1 + nf * 16 + (hi << 2));
      const f32x4 bv = *(const f32x4*)(lnb1 + nf * 16 + (hi << 2));
      const float z0 = (rx[nf][0] - mu) * rs * wv[0] + bv[0];
      const float z1 = (rx[nf][1] - mu) * rs * wv[1] + bv[1];
      const float z2 = (rx[nf][2] - mu) * rs * wv[2] + bv[2];
      const float z3 = (rx[nf][3] - mu) * rs * wv[3] + bv[3];
      pk8[nf * 2] = pkbf(z0, z1);
      pk8[nf * 2 + 1] = pkbf(z2, z3);
    }
    union { uint32_t u[4]; s16x8 v; } f0, f1;
    {
      uint32_t a0l = __shfl(pk8[0], lane_a), a0h = __shfl(pk8[2], lane_a);
      uint32_t a1l = __shfl(pk8[1], lane_a), a1h = __shfl(pk8[3], lane_a);
      uint32_t b0l = __shfl(pk8[0], lane_b), b0h = __shfl(pk8[2], lane_b);
      uint32_t b1l = __shfl(pk8[1], lane_b), b1h = __shfl(pk8[3], lane_b);
      f0.u[0] = hiU ? a0h : a0l;  f0.u[1] = hiU ? a1h : a1l;
      f0.u[2] = hiU ? b0h : b0l;  f0.u[3] = hiU ? b1h : b1l;
    }
    {
      uint32_t a0l = __shfl(pk8[4], lane_a), a0h = __shfl(pk8[6], lane_a);
      uint32_t a1l = __shfl(pk8[5], lane_a), a1h = __shfl(pk8[7], lane_a);
      uint32_t b0l = __shfl(pk8[4], lane_b), b0h = __shfl(pk8[6], lane_b);
      uint32_t b1l = __shfl(pk8[5], lane_b), b1h = __shfl(pk8[7], lane_b);
      f1.u[0] = hiU ? a0h : a0l;  f1.u[1] = hiU ? a1h : a1l;
      f1.u[2] = hiU ? b0h : b0l;  f1.u[3] = hiU ? b1h : b1l;
    }
    xb0 = f0.v; xb1 = f1.v;
  }

  // p1b: scatter tri tile -> transposed Y[j][c^((j>>4)<<4)]
  {
    const int c = t >> 2;
    const int csw = c ^ (q << 4);
#pragma unroll
    for (int s = 0; s < 16; ++s) Y[(q * 16 + s) * APAD + csw] = uu.s[s];
  }
  __syncthreads();   // B1 (drains staging + both Y halves)

  // p2: tri stats + og MFMA (swapped) + y -> Y in place
  const int ybase = jrow * APAD;
  float yv[16];
#pragma unroll
  for (int nf = 0; nf < 4; ++nf) {
    const int pc = (((nf ^ w) & 3) << 4) + (hi << 2);
    const uint2 dd = *(const uint2*)&Y[ybase + pc];
    yv[nf * 4 + 0] = bf2f((unsigned short)(dd.x & 0xffff));
    yv[nf * 4 + 1] = bf2f((unsigned short)(dd.x >> 16));
    yv[nf * 4 + 2] = bf2f((unsigned short)(dd.y & 0xffff));
    yv[nf * 4 + 3] = bf2f((unsigned short)(dd.y >> 16));
  }
  float t1 = 0.f, t2 = 0.f;
#pragma unroll
  for (int s = 0; s < 16; ++s) { t1 += yv[s]; t2 += yv[s] * yv[s]; }
  t1 += __shfl_xor(t1, 16); t2 += __shfl_xor(t2, 16);
  t1 += __shfl_xor(t1, 32); t2 += __shfl_xor(t2, 32);
  const float mu2 = t1 * 0.015625f;
  const float rs2 = rsqrtf(t2 * 0.015625f - mu2 * mu2 + 1e-5f);

#pragma unroll
  for (int nf = 0; nf < 4; ++nf) {
    const int wrow = (nf * 16 + l15) * APAD + kh8;
    const s16x8 wa0 = *(const s16x8*)&WTog[wrow];
    const s16x8 wa1 = *(const s16x8*)&WTog[wrow + 32];
    f32x4 aog = zero4();
    aog = __builtin_amdgcn_mfma_f32_16x16x32_bf16(wa0, xb0, aog, 0, 0, 0);
    aog = __builtin_amdgcn_mfma_f32_16x16x32_bf16(wa1, xb1, aog, 0, 0, 0);
    const f32x4 bg4 = *(const f32x4*)(bog + nf * 16 + (hi << 2));
    const f32x4 wv = *(const f32x4*)(lnw2 + nf * 16 + (hi << 2));
    const f32x4 bv = *(const f32x4*)(lnb2 + nf * 16 + (hi << 2));
    const float y0 = ((yv[nf * 4 + 0] - mu2) * rs2 * wv[0] + bv[0]) * sigmoidf_(aog[0] + bg4[0]);
    const float y1 = ((yv[nf * 4 + 1] - mu2) * rs2 * wv[1] + bv[1]) * sigmoidf_(aog[1] + bg4[1]);
    const float y2 = ((yv[nf * 4 + 2] - mu2) * rs2 * wv[2] + bv[2]) * sigmoidf_(aog[2] + bg4[2]);
    const float y3 = ((yv[nf * 4 + 3] - mu2) * rs2 * wv[3] + bv[3]) * sigmoidf_(aog[3] + bg4[3]);
    uint2 o;
    o.x = pkbf(y0, y1);
    o.y = pkbf(y2, y3);
    const int pc = (((nf ^ w) & 3) << 4) + (hi << 2);
    *(uint2*)&Y[ybase + pc] = o;
  }
  __syncthreads();   // B2

  // p3: out = y @ Wout + bout + resid(regs) -> direct f32x4 stores
  {
    const int xsw = w << 4;
    const s16x8 a0 = *(const s16x8*)&Y[ybase + (kh8 ^ xsw)];
    const s16x8 a1 = *(const s16x8*)&Y[ybase + ((32 + kh8) ^ xsw)];
#pragma unroll
    for (int nf = 0; nf < 4; ++nf) {
      const int brow = (nf * 16 + l15) * APAD + kh8;
      const s16x8 wb0 = *(const s16x8*)&WTout[brow];
      const s16x8 wb1 = *(const s16x8*)&WTout[brow + 32];
      f32x4 ao = zero4();
      ao = __builtin_amdgcn_mfma_f32_16x16x32_bf16(wb0, a0, ao, 0, 0, 0);
      ao = __builtin_amdgcn_mfma_f32_16x16x32_bf16(wb1, a1, ao, 0, 0, 0);
      const f32x4 bo4 = *(const f32x4*)(bout + nf * 16 + (hi << 2));
      f32x4 ov = ao + bo4 + rx[nf];
      *(f32x4*)(outp + rowbase + nf * 16 + (hi << 2)) = ov;
    }
  }
}

// ---------------------------------------------------------------------------
extern "C" void kernel_launch(void* const* d_in, const int* in_sizes, int n_in,
                              void* d_out, int out_size, void* d_ws, size_t ws_size,
                              hipStream_t stream) {
  const float* x     = (const float*)d_in[0];
  const float* mask  = (const float*)d_in[1];
  const float* lnw1  = (const float*)d_in[2];
  const float* lnb1  = (const float*)d_in[3];
  const float* Wlp   = (const float*)d_in[4];
  const float* blp   = (const float*)d_in[5];
  const float* Wrp   = (const float*)d_in[6];
  const float* brp   = (const float*)d_in[7];
  const float* Wlg   = (const float*)d_in[8];
  const float* blg   = (const float*)d_in[9];
  const float* Wrg   = (const float*)d_in[10];
  const float* brg   = (const float*)d_in[11];
  const float* Wog   = (const float*)d_in[12];
  const float* bog   = (const float*)d_in[13];
  const float* lnw2  = (const float*)d_in[14];
  const float* lnb2  = (const float*)d_in[15];
  const float* Wout  = (const float*)d_in[16];
  const float* bout  = (const float*)d_in[17];

  unsigned short* leftT  = (unsigned short*)d_ws;
  unsigned short* rightT = leftT + (size_t)33554432;
  unsigned short* triT   = rightT + (size_t)33554432;
  unsigned short* wt     = triT + (size_t)33554432;   // 6*64*APAD bf16

  k_prep<<<6, 256, 0, stream>>>(Wlp, Wrp, Wlg, Wrg, Wog, Wout, wt);
  k1_proj<<<8192, 256, 0, stream>>>(x, mask, lnw1, lnb1, blp, brp, blg, brg,
                                    wt, leftT, rightT);
  k2_gemm<<<2048, 256, 0, stream>>>(leftT, rightT, triT);
  k3_out<<<4096, 512, 0, stream>>>(triT, x, lnw1, lnb1, bog, lnw2, lnb2, bout,
                                   wt, (float*)d_out);
}